// Round 9
// baseline (32476.263 us; speedup 1.0000x reference)
//
#include <hip/hip_runtime.h>
#include <hip/hip_bf16.h>
#include <stdint.h>

#define NSTEPS 8192
#define DH 1024
#define DIN 512
#define G5 5120
#define NHOUT ((size_t)NSTEPS * DH)

#define NBLK 128   // scan blocks
#define DPB 8      // dims per block (one per wave 0..7)
#define THREADS 576  // 9 waves: 8 dim-waves + 1 poller

typedef __attribute__((ext_vector_type(8))) __bf16 bf16x8;
typedef __attribute__((ext_vector_type(4))) float f32x4;
typedef __attribute__((ext_vector_type(4))) unsigned int u32x4;
typedef __attribute__((ext_vector_type(2))) unsigned int u32x2;

#if __has_builtin(__builtin_amdgcn_fdot2_f32_bf16)
#define HAVE_DOT2 1
typedef __attribute__((ext_vector_type(2))) short s16x2;
__device__ __forceinline__ s16x2 asp(unsigned int u) {
  union { unsigned int i; s16x2 s; } v;
  v.i = u;
  return v.s;
}
#else
#define HAVE_DOT2 0
#endif

__device__ __forceinline__ float bfbits2f(unsigned int u) {
  union { unsigned int i; float f; } v;
  v.i = u << 16;
  return v.f;
}
__device__ __forceinline__ float bfhi2f(unsigned int u) {
  union { unsigned int i; float f; } v;
  v.i = u & 0xffff0000u;
  return v.f;
}
__device__ __forceinline__ unsigned short f2bfbits(float f) {
  union { __bf16 b; unsigned short u; } v;
  v.b = (__bf16)f;
  return v.u;
}
__device__ __forceinline__ unsigned int pk2(float lo, float hi) {
  return (unsigned int)f2bfbits(lo) | ((unsigned int)f2bfbits(hi) << 16);
}

// ---------------- f32 -> bf16 conversion ----------------
__global__ void cvt_f32_bf16(const float* __restrict__ src,
                             unsigned short* __restrict__ dst, int n4) {
  int i = blockIdx.x * blockDim.x + threadIdx.x;
  int stride = gridDim.x * blockDim.x;
  for (; i < n4; i += stride) {
    float4 v = ((const float4*)src)[i];
    ushort4 o;
    o.x = f2bfbits(v.x);
    o.y = f2bfbits(v.y);
    o.z = f2bfbits(v.z);
    o.w = f2bfbits(v.w);
    ((ushort4*)dst)[i] = o;
  }
}

// ------- GEMM: C[m,n] = sum_k A[m,k]*Bt[n,k] + bias[n], bf16 in/out, f32 acc ----
// permute!=0: n = gate*1024 + j  ->  (j>>3)*40 + gate*8 + (j&7)
// i.e. layout [m][block(128)][gate(5)][dim(8)] for the scan's contiguous reads.
#define BM 128
#define BN 128
#define BK 32
#define PSTR 40

__global__ __launch_bounds__(256) void gemm_bt(
    const unsigned short* __restrict__ A,   // [M,K] bf16 bits
    const unsigned short* __restrict__ Bt,  // [N,K] bf16 bits
    const float* __restrict__ bias,         // [N]
    unsigned short* __restrict__ C,         // [M,N] bf16 bits
    int M, int N, int K, int permute) {
  __shared__ unsigned short As[BM * PSTR];
  __shared__ unsigned short Bs[BM * PSTR];
  const int tid = threadIdx.x;
  const int nbn = N / BN;
  const int m0 = (blockIdx.x / nbn) * BM;
  const int n0 = (blockIdx.x % nbn) * BN;
  const int w = tid >> 6;
  const int l = tid & 63;
  const int ln = l & 15;
  const int k8 = l >> 4;
  const int wr = (w >> 1) * 64;
  const int wc = (w & 1) * 64;
  const int row_a = tid >> 2;
  const int c8 = (tid & 3) * 8;

  f32x4 acc[4][4];
#pragma unroll
  for (int a = 0; a < 4; a++)
#pragma unroll
    for (int b = 0; b < 4; b++) acc[a][b] = f32x4{0.f, 0.f, 0.f, 0.f};

  for (int k0 = 0; k0 < K; k0 += BK) {
    uint4 a0 = *(const uint4*)(A + (size_t)(m0 + row_a) * K + k0 + c8);
    uint4 a1 = *(const uint4*)(A + (size_t)(m0 + row_a + 64) * K + k0 + c8);
    uint4 b0 = *(const uint4*)(Bt + (size_t)(n0 + row_a) * K + k0 + c8);
    uint4 b1 = *(const uint4*)(Bt + (size_t)(n0 + row_a + 64) * K + k0 + c8);
    __syncthreads();
    *(uint4*)(As + row_a * PSTR + c8) = a0;
    *(uint4*)(As + (row_a + 64) * PSTR + c8) = a1;
    *(uint4*)(Bs + row_a * PSTR + c8) = b0;
    *(uint4*)(Bs + (row_a + 64) * PSTR + c8) = b1;
    __syncthreads();
    bf16x8 af[4], bfr[4];
#pragma unroll
    for (int mi = 0; mi < 4; mi++)
      af[mi] = *(const bf16x8*)(As + (wr + mi * 16 + ln) * PSTR + k8 * 8);
#pragma unroll
    for (int ni = 0; ni < 4; ni++)
      bfr[ni] = *(const bf16x8*)(Bs + (wc + ni * 16 + ln) * PSTR + k8 * 8);
#pragma unroll
    for (int mi = 0; mi < 4; mi++)
#pragma unroll
      for (int ni = 0; ni < 4; ni++)
        acc[mi][ni] = __builtin_amdgcn_mfma_f32_16x16x32_bf16(
            af[mi], bfr[ni], acc[mi][ni], 0, 0, 0);
  }
#pragma unroll
  for (int ni = 0; ni < 4; ni++) {
    int n = n0 + wc + ni * 16 + ln;
    float bv = bias[n];
#pragma unroll
    for (int mi = 0; mi < 4; mi++) {
#pragma unroll
      for (int r = 0; r < 4; r++) {
        int m = m0 + wr + mi * 16 + k8 * 4 + r;
        size_t ci;
        if (permute) {
          unsigned j = (unsigned)n & 1023u;
          ci = (size_t)m * N +
               (size_t)((j >> 3) * 40u + (((unsigned)n >> 10) << 3) + (j & 7u));
        } else {
          ci = (size_t)m * N + n;
        }
        C[ci] = f2bfbits(acc[mi][ni][r] + bv);
      }
    }
  }
}

// -------- persistent scan: 128 blocks x 9 waves, one dim per wave --------
// wave 8: dedicated poller/stager (double-buffered hpk) — polls h(t) WHILE
//   waves 0-7 compute step t, so detect latency hides under compute.
// waves 0-7: own dim j0+wid. 5 U-rows in 40 VGPRs/lane (lane l = cols
//   16l..16l+15). Per step: 2 ds_read_b128 (h slice) -> 40 dot2 -> 30
//   shfl_xor (all lanes get all 5 sums) -> gates -> lane 0 publishes one
//   tagged word. ONE barrier/step, no s_lds exchange, no W in LDS.
// Tagged words: (tag=t+1)<<16 | bf16(h). Tags 1..8192 never match zero-fill
// or 0xAAAA poison; stale same-tag words from a prior replay carry identical
// data (deterministic recurrence), so no reset is needed.
__global__ __launch_bounds__(THREADS, 1) void scan_kernel(
    const float* __restrict__ times,
    const float* __restrict__ Ui, const float* __restrict__ Uf2,
    const float* __restrict__ Uo, const float* __restrict__ Uz,
    const float* __restrict__ Ud,
    const unsigned short* __restrict__ gxp,  // [NSTEPS][128][40] bf16 bits
    unsigned int* __restrict__ hbuf,         // [2][DH] tagged words
    float* __restrict__ out) {
  __shared__ unsigned int hpk[2][DH / 2];  // packed bf16 pairs of h
  __shared__ float t_lds[NSTEPS];          // 32 KB event times

  const int tid = threadIdx.x;
  const int wid = tid >> 6;
  const int l = tid & 63;
  const int bid = blockIdx.x;
  const int j0 = bid * DPB;

  for (int k = tid; k < NSTEPS / 4; k += THREADS)
    ((float4*)t_lds)[k] = ((const float4*)times)[k];
  for (int k = tid; k < DH / 2; k += THREADS) hpk[0][k] = 0u;

  // ---- W rows (5 gates x own dim) into registers: 5 x 8 u32 per lane ----
  unsigned int W0[8], W1[8], W2[8], W3[8], W4[8];
  unsigned short gn0 = 0, gn1 = 0, gn2 = 0, gn3 = 0, gn4 = 0;
  if (wid < DPB) {
    const float* Us[5] = {Ui, Uf2, Uo, Uz, Ud};
#pragma unroll
    for (int g = 0; g < 5; g++) {
      const float* wr = Us[g] + (size_t)(j0 + wid) * DH + l * 16;
      unsigned int* Wg = (g == 0)   ? W0
                         : (g == 1) ? W1
                         : (g == 2) ? W2
                         : (g == 3) ? W3
                                    : W4;
#pragma unroll
      for (int q = 0; q < 4; q++) {
        float4 v = *(const float4*)(wr + q * 4);
        Wg[q * 2 + 0] = pk2(v.x, v.y);
        Wg[q * 2 + 1] = pk2(v.z, v.w);
      }
    }
    gn0 = gxp[(size_t)0 * G5 + bid * 40 + 0 * 8 + wid];
    gn1 = gxp[(size_t)0 * G5 + bid * 40 + 1 * 8 + wid];
    gn2 = gxp[(size_t)0 * G5 + bid * 40 + 2 * 8 + wid];
    gn3 = gxp[(size_t)0 * G5 + bid * 40 + 3 * 8 + wid];
    gn4 = gxp[(size_t)0 * G5 + bid * 40 + 4 * 8 + wid];
  }
  float cbv = 0.f, cd_reg = 0.f;  // state (all lanes of each dim-wave)
  __syncthreads();

  for (int t = 0; t < NSTEPS; ++t) {
    if (wid == 8 && t > 0) {  // poller: h(t-1) -> hpk[t&1]
      const unsigned int want = (unsigned int)t;  // tag = (t-1)+1
      const u32x4* pb = (const u32x4*)(hbuf + ((t - 1) & 1) * DH) + l;
      u32x4 A, B, C2, D2;
      for (;;) {
        asm volatile(
            "global_load_dwordx4 %0, %4, off sc1\n\t"
            "global_load_dwordx4 %1, %4, off offset:1024 sc1\n\t"
            "global_load_dwordx4 %2, %4, off offset:2048 sc1\n\t"
            "global_load_dwordx4 %3, %4, off offset:3072 sc1\n\t"
            "s_waitcnt vmcnt(0)"
            : "=&v"(A), "=&v"(B), "=&v"(C2), "=&v"(D2)
            : "v"(pb)
            : "memory");
        bool ok = (A[0] >> 16) == want && (A[1] >> 16) == want &&
                  (A[2] >> 16) == want && (A[3] >> 16) == want &&
                  (B[0] >> 16) == want && (B[1] >> 16) == want &&
                  (B[2] >> 16) == want && (B[3] >> 16) == want &&
                  (C2[0] >> 16) == want && (C2[1] >> 16) == want &&
                  (C2[2] >> 16) == want && (C2[3] >> 16) == want &&
                  (D2[0] >> 16) == want && (D2[1] >> 16) == want &&
                  (D2[2] >> 16) == want && (D2[3] >> 16) == want;
        if (__all(ok)) break;
      }
      unsigned int* hp = hpk[t & 1];
      *(u32x2*)(hp + 2 * l) =
          u32x2{(A[0] & 0xffffu) | (A[1] << 16), (A[2] & 0xffffu) | (A[3] << 16)};
      *(u32x2*)(hp + 128 + 2 * l) =
          u32x2{(B[0] & 0xffffu) | (B[1] << 16), (B[2] & 0xffffu) | (B[3] << 16)};
      *(u32x2*)(hp + 256 + 2 * l) = u32x2{(C2[0] & 0xffffu) | (C2[1] << 16),
                                          (C2[2] & 0xffffu) | (C2[3] << 16)};
      *(u32x2*)(hp + 384 + 2 * l) = u32x2{(D2[0] & 0xffffu) | (D2[1] << 16),
                                          (D2[2] & 0xffffu) | (D2[3] << 16)};
    }
    __syncthreads();  // b1: hpk[t&1] holds h(t-1); poller races ahead after

    if (wid < DPB) {
      // gx for this step (loaded a full step ago), convert at use
      float gx0 = bfbits2f((unsigned int)gn0);
      float gx1 = bfbits2f((unsigned int)gn1);
      float gx2 = bfbits2f((unsigned int)gn2);
      float gx3 = bfbits2f((unsigned int)gn3);
      float gx4 = bfbits2f((unsigned int)gn4);
      float tc = t_lds[t];
      float tn = t_lds[t + (t < NSTEPS - 1 ? 1 : 0)];

      // h slice: lane l holds h[16l..16l+15] packed
      const unsigned int* hp = hpk[t & 1];
      u32x4 ha = *(const u32x4*)(hp + 8 * l);
      u32x4 hb = *(const u32x4*)(hp + 8 * l + 4);

      float s0 = 0.f, s1 = 0.f, s2 = 0.f, s3 = 0.f, s4 = 0.f;
#if HAVE_DOT2
#pragma unroll
      for (int k = 0; k < 4; k++) {
        s0 = __builtin_amdgcn_fdot2_f32_bf16(asp(W0[k]), asp(ha[k]), s0, false);
        s1 = __builtin_amdgcn_fdot2_f32_bf16(asp(W1[k]), asp(ha[k]), s1, false);
        s2 = __builtin_amdgcn_fdot2_f32_bf16(asp(W2[k]), asp(ha[k]), s2, false);
        s3 = __builtin_amdgcn_fdot2_f32_bf16(asp(W3[k]), asp(ha[k]), s3, false);
        s4 = __builtin_amdgcn_fdot2_f32_bf16(asp(W4[k]), asp(ha[k]), s4, false);
      }
#pragma unroll
      for (int k = 0; k < 4; k++) {
        s0 = __builtin_amdgcn_fdot2_f32_bf16(asp(W0[k + 4]), asp(hb[k]), s0, false);
        s1 = __builtin_amdgcn_fdot2_f32_bf16(asp(W1[k + 4]), asp(hb[k]), s1, false);
        s2 = __builtin_amdgcn_fdot2_f32_bf16(asp(W2[k + 4]), asp(hb[k]), s2, false);
        s3 = __builtin_amdgcn_fdot2_f32_bf16(asp(W3[k + 4]), asp(hb[k]), s3, false);
        s4 = __builtin_amdgcn_fdot2_f32_bf16(asp(W4[k + 4]), asp(hb[k]), s4, false);
      }
#else
#pragma unroll
      for (int k = 0; k < 4; k++) {
        s0 += bfbits2f(W0[k] & 0xffffu) * bfbits2f(ha[k] & 0xffffu) +
              bfhi2f(W0[k]) * bfhi2f(ha[k]);
        s1 += bfbits2f(W1[k] & 0xffffu) * bfbits2f(ha[k] & 0xffffu) +
              bfhi2f(W1[k]) * bfhi2f(ha[k]);
        s2 += bfbits2f(W2[k] & 0xffffu) * bfbits2f(ha[k] & 0xffffu) +
              bfhi2f(W2[k]) * bfhi2f(ha[k]);
        s3 += bfbits2f(W3[k] & 0xffffu) * bfbits2f(ha[k] & 0xffffu) +
              bfhi2f(W3[k]) * bfhi2f(ha[k]);
        s4 += bfbits2f(W4[k] & 0xffffu) * bfbits2f(ha[k] & 0xffffu) +
              bfhi2f(W4[k]) * bfhi2f(ha[k]);
        s0 += bfbits2f(W0[k + 4] & 0xffffu) * bfbits2f(hb[k] & 0xffffu) +
              bfhi2f(W0[k + 4]) * bfhi2f(hb[k]);
        s1 += bfbits2f(W1[k + 4] & 0xffffu) * bfbits2f(hb[k] & 0xffffu) +
              bfhi2f(W1[k + 4]) * bfhi2f(hb[k]);
        s2 += bfbits2f(W2[k + 4] & 0xffffu) * bfbits2f(hb[k] & 0xffffu) +
              bfhi2f(W2[k + 4]) * bfhi2f(hb[k]);
        s3 += bfbits2f(W3[k + 4] & 0xffffu) * bfbits2f(hb[k] & 0xffffu) +
              bfhi2f(W3[k + 4]) * bfhi2f(hb[k]);
        s4 += bfbits2f(W4[k + 4] & 0xffffu) * bfbits2f(hb[k] & 0xffffu) +
              bfhi2f(W4[k + 4]) * bfhi2f(hb[k]);
      }
#endif
      // full-wave reduce: every lane ends with all 5 sums
#pragma unroll
      for (int off = 1; off < 64; off <<= 1) {
        s0 += __shfl_xor(s0, off);
        s1 += __shfl_xor(s1, off);
        s2 += __shfl_xor(s2, off);
        s3 += __shfl_xor(s3, off);
        s4 += __shfl_xor(s4, off);
      }

      // gates (redundant across lanes)
      float ig = 1.f / (1.f + __expf(-(s0 + gx0)));
      float fg = 1.f / (1.f + __expf(-(s1 + gx1)));
      float og = 1.f / (1.f + __expf(-(s2 + gx2)));
      float z = 1.f - 2.f / (__expf(2.f * (s3 + gx3)) + 1.f);
      float cn = fg * cd_reg + ig * z;
      float th = 1.f - 2.f / (__expf(2.f * cn) + 1.f);
      float h = og * th;
      unsigned int word =
          (((unsigned int)(t + 1) & 0xffffu) << 16) | (unsigned int)f2bfbits(h);
      if (l == 0) {  // publish this dim's word ASAP
        unsigned int* dst = hbuf + (t & 1) * DH + j0 + wid;
        asm volatile("global_store_dword %0, %1, off sc1" ::"v"(dst), "v"(word)
                     : "memory");
      }
      // prefetch gx(t+1) (consumed next step; full step of flight)
      {
        int tf = t + 1 < NSTEPS ? t + 1 : t;
        const unsigned short* gp = gxp + (size_t)tf * G5 + bid * 40 + wid;
        gn0 = gp[0];
        gn1 = gp[8];
        gn2 = gp[16];
        gn3 = gp[24];
        gn4 = gp[32];
      }
      // deferred state + outputs
      float sd = s4 + gx4;
      float dec = fmaxf(sd, 0.f) + __logf(1.f + __expf(-fabsf(sd)));
      cbv = fg * cbv + ig * z;
      cd_reg = cbv + (cn - cbv) * __expf(-dec * (tn - tc));
      if (l == 0) {
        int j = j0 + wid;
        out[(size_t)t * DH + j] = h;
        out[NHOUT + (size_t)t * DH + j] = cn;
        out[2 * NHOUT + (size_t)t * DH + j] = dec;
      }
    }
    // poller (wid==8) loops straight into polling h(t).
  }
  if (wid < DPB && l == 0) out[3 * NHOUT + j0 + wid] = cbv;
}

extern "C" void kernel_launch(void* const* d_in, const int* in_sizes, int n_in,
                              void* d_out, int out_size, void* d_ws,
                              size_t ws_size, hipStream_t stream) {
  (void)in_sizes; (void)n_in; (void)out_size; (void)ws_size;
  const float* times = (const float*)d_in[0];
  const float* marks = (const float*)d_in[1];
  const float* Wp = (const float*)d_in[3];
  const float* bp = (const float*)d_in[4];
  const float* Wi = (const float*)d_in[5];
  const float* bi = (const float*)d_in[6];
  const float* Wf = (const float*)d_in[7];
  const float* bf_ = (const float*)d_in[8];
  const float* Wo = (const float*)d_in[9];
  const float* bo = (const float*)d_in[10];
  const float* Wz = (const float*)d_in[11];
  const float* bz = (const float*)d_in[12];
  const float* Wd = (const float*)d_in[13];
  const float* bd = (const float*)d_in[14];
  const float* Ui = (const float*)d_in[15];
  const float* Uf2 = (const float*)d_in[16];
  const float* Uo = (const float*)d_in[17];
  const float* Uz = (const float*)d_in[18];
  const float* Ud = (const float*)d_in[19];

  char* ws = (char*)d_ws;
  size_t off = 0;
  auto alloc = [&](size_t bytes) -> void* {
    void* p = ws + off;
    off += (bytes + 255) & ~(size_t)255;
    return p;
  };
  unsigned short* marks_bf = (unsigned short*)alloc((size_t)NSTEPS * DIN * 2);
  unsigned short* X_bf = (unsigned short*)alloc((size_t)NSTEPS * DH * 2);
  unsigned short* Wp_bf = (unsigned short*)alloc((size_t)DH * DIN * 2);
  unsigned short* W5_bf = (unsigned short*)alloc((size_t)G5 * DH * 2);
  float* bcat = (float*)alloc((size_t)G5 * 4);
  unsigned short* gxp = (unsigned short*)alloc((size_t)NSTEPS * G5 * 2);
  unsigned int* hbuf = (unsigned int*)alloc((size_t)2 * DH * 4);

  auto cvt = [&](const float* s, unsigned short* d, int n) {
    int n4 = n / 4;
    int grid = (n4 + 255) / 256;
    if (grid > 2048) grid = 2048;
    cvt_f32_bf16<<<grid, 256, 0, stream>>>(s, d, n4);
  };
  cvt(marks, marks_bf, NSTEPS * DIN);
  cvt(Wp, Wp_bf, DH * DIN);
  cvt(Wi, W5_bf + (size_t)0 * DH * DH, DH * DH);
  cvt(Wf, W5_bf + (size_t)1 * DH * DH, DH * DH);
  cvt(Wo, W5_bf + (size_t)2 * DH * DH, DH * DH);
  cvt(Wz, W5_bf + (size_t)3 * DH * DH, DH * DH);
  cvt(Wd, W5_bf + (size_t)4 * DH * DH, DH * DH);
  hipMemcpyAsync(bcat + 0 * DH, bi, DH * sizeof(float),
                 hipMemcpyDeviceToDevice, stream);
  hipMemcpyAsync(bcat + 1 * DH, bf_, DH * sizeof(float),
                 hipMemcpyDeviceToDevice, stream);
  hipMemcpyAsync(bcat + 2 * DH, bo, DH * sizeof(float),
                 hipMemcpyDeviceToDevice, stream);
  hipMemcpyAsync(bcat + 3 * DH, bz, DH * sizeof(float),
                 hipMemcpyDeviceToDevice, stream);
  hipMemcpyAsync(bcat + 4 * DH, bd, DH * sizeof(float),
                 hipMemcpyDeviceToDevice, stream);

  // X = marks @ Wp.T + bp   [8192,1024]
  gemm_bt<<<(NSTEPS / BM) * (DH / BN), 256, 0, stream>>>(
      marks_bf, Wp_bf, bp, X_bf, NSTEPS, DH, DIN, 0);
  // gxp = permute(X @ [Wi;Wf;Wo;Wz;Wd].T + bcat)   [8192][128][5][8]
  gemm_bt<<<(NSTEPS / BM) * (G5 / BN), 256, 0, stream>>>(
      X_bf, W5_bf, bcat, gxp, NSTEPS, G5, DH, 1);

  scan_kernel<<<NBLK, THREADS, 0, stream>>>(times, Ui, Uf2, Uo, Uz, Ud, gxp,
                                            hbuf, (float*)d_out);
}

// Round 10
// 14577.110 us; speedup vs baseline: 2.2279x; 2.2279x over previous
//
#include <hip/hip_runtime.h>
#include <hip/hip_bf16.h>
#include <stdint.h>

#define NSTEPS 8192
#define DH 1024
#define DIN 512
#define G5 5120
#define NHOUT ((size_t)NSTEPS * DH)

#define NBLK 128   // scan blocks
#define DPB 8      // dims per block
#define WROWS 40   // 5 gates * DPB
#define THREADS 320

typedef __attribute__((ext_vector_type(8))) __bf16 bf16x8;
typedef __attribute__((ext_vector_type(4))) float f32x4;
typedef __attribute__((ext_vector_type(4))) unsigned int u32x4;
typedef __attribute__((ext_vector_type(2))) unsigned int u32x2;

#if __has_builtin(__builtin_amdgcn_fdot2_f32_bf16)
#define HAVE_DOT2 1
typedef __attribute__((ext_vector_type(2))) short s16x2;
__device__ __forceinline__ s16x2 asp(unsigned int u) {
  union { unsigned int i; s16x2 s; } v;
  v.i = u;
  return v.s;
}
#else
#define HAVE_DOT2 0
#endif

__device__ __forceinline__ float bfbits2f(unsigned int u) {
  union { unsigned int i; float f; } v;
  v.i = u << 16;
  return v.f;
}
__device__ __forceinline__ float bfhi2f(unsigned int u) {
  union { unsigned int i; float f; } v;
  v.i = u & 0xffff0000u;
  return v.f;
}
__device__ __forceinline__ unsigned short f2bfbits(float f) {
  union { __bf16 b; unsigned short u; } v;
  v.b = (__bf16)f;
  return v.u;
}

// ---------------- f32 -> bf16 conversion ----------------
__global__ void cvt_f32_bf16(const float* __restrict__ src,
                             unsigned short* __restrict__ dst, int n4) {
  int i = blockIdx.x * blockDim.x + threadIdx.x;
  int stride = gridDim.x * blockDim.x;
  for (; i < n4; i += stride) {
    float4 v = ((const float4*)src)[i];
    ushort4 o;
    o.x = f2bfbits(v.x);
    o.y = f2bfbits(v.y);
    o.z = f2bfbits(v.z);
    o.w = f2bfbits(v.w);
    ((ushort4*)dst)[i] = o;
  }
}

// ------- GEMM: C[m,n] = sum_k A[m,k]*Bt[n,k] + bias[n], bf16 in/out, f32 acc ----
// permute!=0: n = gate*1024 + j  ->  (j>>3)*40 + gate*8 + (j&7)
// i.e. layout [m][block(128)][gate(5)][dim(8)] for the scan's contiguous reads.
#define BM 128
#define BN 128
#define BK 32
#define PSTR 40

__global__ __launch_bounds__(256) void gemm_bt(
    const unsigned short* __restrict__ A,   // [M,K] bf16 bits
    const unsigned short* __restrict__ Bt,  // [N,K] bf16 bits
    const float* __restrict__ bias,         // [N]
    unsigned short* __restrict__ C,         // [M,N] bf16 bits
    int M, int N, int K, int permute) {
  __shared__ unsigned short As[BM * PSTR];
  __shared__ unsigned short Bs[BM * PSTR];
  const int tid = threadIdx.x;
  const int nbn = N / BN;
  const int m0 = (blockIdx.x / nbn) * BM;
  const int n0 = (blockIdx.x % nbn) * BN;
  const int w = tid >> 6;
  const int l = tid & 63;
  const int ln = l & 15;
  const int k8 = l >> 4;
  const int wr = (w >> 1) * 64;
  const int wc = (w & 1) * 64;
  const int row_a = tid >> 2;
  const int c8 = (tid & 3) * 8;

  f32x4 acc[4][4];
#pragma unroll
  for (int a = 0; a < 4; a++)
#pragma unroll
    for (int b = 0; b < 4; b++) acc[a][b] = f32x4{0.f, 0.f, 0.f, 0.f};

  for (int k0 = 0; k0 < K; k0 += BK) {
    uint4 a0 = *(const uint4*)(A + (size_t)(m0 + row_a) * K + k0 + c8);
    uint4 a1 = *(const uint4*)(A + (size_t)(m0 + row_a + 64) * K + k0 + c8);
    uint4 b0 = *(const uint4*)(Bt + (size_t)(n0 + row_a) * K + k0 + c8);
    uint4 b1 = *(const uint4*)(Bt + (size_t)(n0 + row_a + 64) * K + k0 + c8);
    __syncthreads();
    *(uint4*)(As + row_a * PSTR + c8) = a0;
    *(uint4*)(As + (row_a + 64) * PSTR + c8) = a1;
    *(uint4*)(Bs + row_a * PSTR + c8) = b0;
    *(uint4*)(Bs + (row_a + 64) * PSTR + c8) = b1;
    __syncthreads();
    bf16x8 af[4], bfr[4];
#pragma unroll
    for (int mi = 0; mi < 4; mi++)
      af[mi] = *(const bf16x8*)(As + (wr + mi * 16 + ln) * PSTR + k8 * 8);
#pragma unroll
    for (int ni = 0; ni < 4; ni++)
      bfr[ni] = *(const bf16x8*)(Bs + (wc + ni * 16 + ln) * PSTR + k8 * 8);
#pragma unroll
    for (int mi = 0; mi < 4; mi++)
#pragma unroll
      for (int ni = 0; ni < 4; ni++)
        acc[mi][ni] = __builtin_amdgcn_mfma_f32_16x16x32_bf16(
            af[mi], bfr[ni], acc[mi][ni], 0, 0, 0);
  }
#pragma unroll
  for (int ni = 0; ni < 4; ni++) {
    int n = n0 + wc + ni * 16 + ln;
    float bv = bias[n];
#pragma unroll
    for (int mi = 0; mi < 4; mi++) {
#pragma unroll
      for (int r = 0; r < 4; r++) {
        int m = m0 + wr + mi * 16 + k8 * 4 + r;
        size_t ci;
        if (permute) {
          unsigned j = (unsigned)n & 1023u;
          ci = (size_t)m * N +
               (size_t)((j >> 3) * 40u + (((unsigned)n >> 10) << 3) + (j & 7u));
        } else {
          ci = (size_t)m * N + n;
        }
        C[ci] = f2bfbits(acc[mi][ni][r] + bv);
      }
    }
  }
}

// ---------------- persistent scan: 128 blocks, 8 dims each ----------------
// EXACT r3 structure (best measured: 16.0 ms) with ONE change: W stored in
// LDS retiled as w2[i][row][ln8] 16B units so each wave's 64 ds_read_b128
// cover 1KB contiguous -> bank-conflict-free (r3's WSTR layout measured
// 6.8e8 conflict cycles).
// Tagged words: (tag=t+1)<<16 | bf16(h). Wide sc1 loads/stores; only wave 0
// polls. Tags 1..8192 never match zero-fill or 0xAAAA poison; stale same-tag
// words from a prior replay carry identical data (deterministic recurrence).
__global__ __launch_bounds__(THREADS) void scan_kernel(
    const float* __restrict__ times,
    const float* __restrict__ Ui, const float* __restrict__ Uf2,
    const float* __restrict__ Uo, const float* __restrict__ Uz,
    const float* __restrict__ Ud,
    const unsigned short* __restrict__ gxp,  // [NSTEPS][128][40] bf16 bits
    unsigned int* __restrict__ hbuf,         // [2][DH] tagged words
    float* __restrict__ out) {
  __shared__ u32x4 w2[16 * WROWS * 8];  // 80 KB: [i][row][ln8] 16B units
#if HAVE_DOT2
  __shared__ unsigned int hpk[DH / 2];  // packed bf16 pairs
#else
  __shared__ float hf[DH];
#endif
  __shared__ float s_lds[WROWS];

  const int tid = threadIdx.x;
  const int bid = blockIdx.x;
  const int j0 = bid * DPB;

  {  // stage this block's 40 U-rows into LDS as bf16 (read once from HBM)
    const float* Us[5] = {Ui, Uf2, Uo, Uz, Ud};
    for (int idx = tid; idx < WROWS * 256; idx += THREADS) {
      int row = idx >> 8;
      int c4 = idx & 255;  // covers cols 4*c4 .. 4*c4+3
      const float* src =
          Us[row >> 3] + (size_t)(j0 + (row & 7)) * DH + c4 * 4;
      float4 v = *(const float4*)src;
      ushort4 o;
      o.x = f2bfbits(v.x);
      o.y = f2bfbits(v.y);
      o.z = f2bfbits(v.z);
      o.w = f2bfbits(v.w);
      int i16 = c4 >> 4;             // which 64-col slab
      int ln = (c4 & 15) >> 1;       // which 16B unit in slab
      int half = c4 & 1;             // which 8B half
      *(ushort4*)((char*)(w2 + (i16 * WROWS + row) * 8 + ln) + half * 8) = o;
    }
  }
#if HAVE_DOT2
  for (int k = tid; k < DH / 2; k += THREADS) hpk[k] = 0u;
#else
  for (int k = tid; k < DH; k += THREADS) hf[k] = 0.f;
#endif
  // per-dim state lives in lanes tid<8 of wave 0
  float c = 0.f, cbv = 0.f, cd_reg = 0.f;
  __syncthreads();

  const int row = tid >> 3;   // 0..39
  const int ln8 = tid & 7;
  const u32x4* w2p = w2 + row * 8 + ln8;  // index by i*WROWS*8

  for (int t = 0; t < NSTEPS; ++t) {
    // issue independent loads early; their latency hides under the poll
    float gval = 0.f;
    float tcur = 0.f;
    if (tid < WROWS)
      gval = bfbits2f((unsigned int)gxp[(size_t)t * G5 + bid * WROWS + tid]);
    if (tid < DPB) tcur = times[t];

    if (t > 0 && tid < 64) {  // wave 0: poll h(t-1), repack into LDS
      const unsigned int want = (unsigned int)t;  // tag = (t-1)+1
      const u32x4* pb = (const u32x4*)(hbuf + ((t - 1) & 1) * DH) + tid;
      u32x4 A, B, C2, D2;
      for (;;) {
        asm volatile(
            "global_load_dwordx4 %0, %4, off sc1\n\t"
            "global_load_dwordx4 %1, %4, off offset:1024 sc1\n\t"
            "global_load_dwordx4 %2, %4, off offset:2048 sc1\n\t"
            "global_load_dwordx4 %3, %4, off offset:3072 sc1\n\t"
            "s_waitcnt vmcnt(0)"
            : "=&v"(A), "=&v"(B), "=&v"(C2), "=&v"(D2)
            : "v"(pb)
            : "memory");
        bool ok = (A[0] >> 16) == want && (A[1] >> 16) == want &&
                  (A[2] >> 16) == want && (A[3] >> 16) == want &&
                  (B[0] >> 16) == want && (B[1] >> 16) == want &&
                  (B[2] >> 16) == want && (B[3] >> 16) == want &&
                  (C2[0] >> 16) == want && (C2[1] >> 16) == want &&
                  (C2[2] >> 16) == want && (C2[3] >> 16) == want &&
                  (D2[0] >> 16) == want && (D2[1] >> 16) == want &&
                  (D2[2] >> 16) == want && (D2[3] >> 16) == want;
        if (__all(ok)) break;
      }
#if HAVE_DOT2
      u32x2 pA = {(A[0] & 0xffffu) | (A[1] << 16),
                  (A[2] & 0xffffu) | (A[3] << 16)};
      u32x2 pB = {(B[0] & 0xffffu) | (B[1] << 16),
                  (B[2] & 0xffffu) | (B[3] << 16)};
      u32x2 pC = {(C2[0] & 0xffffu) | (C2[1] << 16),
                  (C2[2] & 0xffffu) | (C2[3] << 16)};
      u32x2 pD = {(D2[0] & 0xffffu) | (D2[1] << 16),
                  (D2[2] & 0xffffu) | (D2[3] << 16)};
      *(u32x2*)(hpk + 2 * tid) = pA;
      *(u32x2*)(hpk + 128 + 2 * tid) = pB;
      *(u32x2*)(hpk + 256 + 2 * tid) = pC;
      *(u32x2*)(hpk + 384 + 2 * tid) = pD;
#else
      f32x4 o0 = {bfbits2f(A[0] & 0xffffu), bfbits2f(A[1] & 0xffffu),
                  bfbits2f(A[2] & 0xffffu), bfbits2f(A[3] & 0xffffu)};
      f32x4 o1 = {bfbits2f(B[0] & 0xffffu), bfbits2f(B[1] & 0xffffu),
                  bfbits2f(B[2] & 0xffffu), bfbits2f(B[3] & 0xffffu)};
      f32x4 o2 = {bfbits2f(C2[0] & 0xffffu), bfbits2f(C2[1] & 0xffffu),
                  bfbits2f(C2[2] & 0xffffu), bfbits2f(C2[3] & 0xffffu)};
      f32x4 o3 = {bfbits2f(D2[0] & 0xffffu), bfbits2f(D2[1] & 0xffffu),
                  bfbits2f(D2[2] & 0xffffu), bfbits2f(D2[3] & 0xffffu)};
      *(f32x4*)(hf + 0 + 4 * tid) = o0;
      *(f32x4*)(hf + 256 + 4 * tid) = o1;
      *(f32x4*)(hf + 512 + 4 * tid) = o2;
      *(f32x4*)(hf + 768 + 4 * tid) = o3;
#endif
    }
    __syncthreads();  // h ready (zeros at t==0)

    // matvec: 40 rows x 1024, 8 lanes per row, all 320 lanes active
    {
#if HAVE_DOT2
      float a0 = 0.f, a1 = 0.f, a2 = 0.f, a3 = 0.f;
#pragma unroll
      for (int i = 0; i < 16; i++) {
        u32x4 wv = w2p[i * WROWS * 8];
        u32x4 hv = *(const u32x4*)(hpk + i * 32 + ln8 * 4);
        a0 = __builtin_amdgcn_fdot2_f32_bf16(asp(wv[0]), asp(hv[0]), a0, false);
        a1 = __builtin_amdgcn_fdot2_f32_bf16(asp(wv[1]), asp(hv[1]), a1, false);
        a2 = __builtin_amdgcn_fdot2_f32_bf16(asp(wv[2]), asp(hv[2]), a2, false);
        a3 = __builtin_amdgcn_fdot2_f32_bf16(asp(wv[3]), asp(hv[3]), a3, false);
      }
      float s = (a0 + a1) + (a2 + a3);
#else
      float a0 = 0.f, a1 = 0.f;
#pragma unroll
      for (int i = 0; i < 16; i++) {
        u32x4 wv = w2p[i * WROWS * 8];
        const float* hp = hf + i * 64 + ln8 * 8;
        f32x4 h0 = *(const f32x4*)hp;
        f32x4 h1 = *(const f32x4*)(hp + 4);
        a0 += bfbits2f(wv[0] & 0xffffu) * h0[0];
        a1 += bfhi2f(wv[0]) * h0[1];
        a0 += bfbits2f(wv[1] & 0xffffu) * h0[2];
        a1 += bfhi2f(wv[1]) * h0[3];
        a0 += bfbits2f(wv[2] & 0xffffu) * h1[0];
        a1 += bfhi2f(wv[2]) * h1[1];
        a0 += bfbits2f(wv[3] & 0xffffu) * h1[2];
        a1 += bfhi2f(wv[3]) * h1[3];
      }
      float s = a0 + a1;
#endif
      s += __shfl_xor(s, 1);
      s += __shfl_xor(s, 2);
      s += __shfl_xor(s, 4);
      if (ln8 == 0) s_lds[row] = s;
    }
    __syncthreads();  // s_lds ready

    if (tid < 64) {  // wave 0: gates -> publish ASAP -> deferred work
      const int d = tid & 7;
      float xi = __shfl(gval, d);
      float xf2 = __shfl(gval, 8 + d);
      float xo = __shfl(gval, 16 + d);
      float xz = __shfl(gval, 24 + d);
      float xd = __shfl(gval, 32 + d);
      unsigned int word = 0;
      float h = 0.f, cn = 0.f, ig = 0.f, fg = 0.f, z = 0.f, adv = 0.f;
      if (tid < DPB) {
        float si = s_lds[tid];
        float sf = s_lds[8 + tid];
        float so = s_lds[16 + tid];
        float sz = s_lds[24 + tid];
        float sd = s_lds[32 + tid];
        ig = 1.f / (1.f + __expf(-(xi + si)));
        fg = 1.f / (1.f + __expf(-(xf2 + sf)));
        float og = 1.f / (1.f + __expf(-(xo + so)));
        z = 1.f - 2.f / (__expf(2.f * (xz + sz)) + 1.f);
        cn = fg * cd_reg + ig * z;
        float th = 1.f - 2.f / (__expf(2.f * cn) + 1.f);
        h = og * th;
        adv = xd + sd;
        word =
            (((unsigned int)(t + 1) & 0xffffu) << 16) | (unsigned int)f2bfbits(h);
      }
      u32x4 pubv = {__shfl(word, 4 * tid + 0), __shfl(word, 4 * tid + 1),
                    __shfl(word, 4 * tid + 2), __shfl(word, 4 * tid + 3)};
      if (tid < 2) {
        u32x4* dst = (u32x4*)(hbuf + (t & 1) * DH + bid * DPB) + tid;
        asm volatile("global_store_dwordx4 %0, %1, off sc1" ::"v"(dst),
                     "v"(pubv)
                     : "memory");
      }
      // ---- off the publish-critical path ----
      if (tid < DPB) {
        float dec = fmaxf(adv, 0.f) + __logf(1.f + __expf(-fabsf(adv)));
        cbv = fg * cbv + ig * z;
        c = cn;
        int j = j0 + tid;
        out[(size_t)t * DH + j] = h;
        out[NHOUT + (size_t)t * DH + j] = cn;
        out[2 * NHOUT + (size_t)t * DH + j] = dec;
        float tn = times[t + (t < NSTEPS - 1 ? 1 : 0)];
        cd_reg = cbv + (cn - cbv) * __expf(-dec * (tn - tcur));
      }
    }
    // no trailing barrier: waves 1-4 park at the next iteration's first
    // barrier while wave 0 finishes publish + deferred work + next poll.
  }
  if (tid < DPB) out[3 * NHOUT + j0 + tid] = cbv;
}

extern "C" void kernel_launch(void* const* d_in, const int* in_sizes, int n_in,
                              void* d_out, int out_size, void* d_ws,
                              size_t ws_size, hipStream_t stream) {
  (void)in_sizes; (void)n_in; (void)out_size; (void)ws_size;
  const float* times = (const float*)d_in[0];
  const float* marks = (const float*)d_in[1];
  const float* Wp = (const float*)d_in[3];
  const float* bp = (const float*)d_in[4];
  const float* Wi = (const float*)d_in[5];
  const float* bi = (const float*)d_in[6];
  const float* Wf = (const float*)d_in[7];
  const float* bf_ = (const float*)d_in[8];
  const float* Wo = (const float*)d_in[9];
  const float* bo = (const float*)d_in[10];
  const float* Wz = (const float*)d_in[11];
  const float* bz = (const float*)d_in[12];
  const float* Wd = (const float*)d_in[13];
  const float* bd = (const float*)d_in[14];
  const float* Ui = (const float*)d_in[15];
  const float* Uf2 = (const float*)d_in[16];
  const float* Uo = (const float*)d_in[17];
  const float* Uz = (const float*)d_in[18];
  const float* Ud = (const float*)d_in[19];

  char* ws = (char*)d_ws;
  size_t off = 0;
  auto alloc = [&](size_t bytes) -> void* {
    void* p = ws + off;
    off += (bytes + 255) & ~(size_t)255;
    return p;
  };
  unsigned short* marks_bf = (unsigned short*)alloc((size_t)NSTEPS * DIN * 2);
  unsigned short* X_bf = (unsigned short*)alloc((size_t)NSTEPS * DH * 2);
  unsigned short* Wp_bf = (unsigned short*)alloc((size_t)DH * DIN * 2);
  unsigned short* W5_bf = (unsigned short*)alloc((size_t)G5 * DH * 2);
  float* bcat = (float*)alloc((size_t)G5 * 4);
  unsigned short* gxp = (unsigned short*)alloc((size_t)NSTEPS * G5 * 2);
  unsigned int* hbuf = (unsigned int*)alloc((size_t)2 * DH * 4);

  auto cvt = [&](const float* s, unsigned short* d, int n) {
    int n4 = n / 4;
    int grid = (n4 + 255) / 256;
    if (grid > 2048) grid = 2048;
    cvt_f32_bf16<<<grid, 256, 0, stream>>>(s, d, n4);
  };
  cvt(marks, marks_bf, NSTEPS * DIN);
  cvt(Wp, Wp_bf, DH * DIN);
  cvt(Wi, W5_bf + (size_t)0 * DH * DH, DH * DH);
  cvt(Wf, W5_bf + (size_t)1 * DH * DH, DH * DH);
  cvt(Wo, W5_bf + (size_t)2 * DH * DH, DH * DH);
  cvt(Wz, W5_bf + (size_t)3 * DH * DH, DH * DH);
  cvt(Wd, W5_bf + (size_t)4 * DH * DH, DH * DH);
  hipMemcpyAsync(bcat + 0 * DH, bi, DH * sizeof(float),
                 hipMemcpyDeviceToDevice, stream);
  hipMemcpyAsync(bcat + 1 * DH, bf_, DH * sizeof(float),
                 hipMemcpyDeviceToDevice, stream);
  hipMemcpyAsync(bcat + 2 * DH, bo, DH * sizeof(float),
                 hipMemcpyDeviceToDevice, stream);
  hipMemcpyAsync(bcat + 3 * DH, bz, DH * sizeof(float),
                 hipMemcpyDeviceToDevice, stream);
  hipMemcpyAsync(bcat + 4 * DH, bd, DH * sizeof(float),
                 hipMemcpyDeviceToDevice, stream);

  // X = marks @ Wp.T + bp   [8192,1024]
  gemm_bt<<<(NSTEPS / BM) * (DH / BN), 256, 0, stream>>>(
      marks_bf, Wp_bf, bp, X_bf, NSTEPS, DH, DIN, 0);
  // gxp = permute(X @ [Wi;Wf;Wo;Wz;Wd].T + bcat)   [8192][128][5][8]
  gemm_bt<<<(NSTEPS / BM) * (G5 / BN), 256, 0, stream>>>(
      X_bf, W5_bf, bcat, gxp, NSTEPS, G5, DH, 1);

  scan_kernel<<<NBLK, THREADS, 0, stream>>>(times, Ui, Uf2, Uo, Uz, Ud, gxp,
                                            hbuf, (float*)d_out);
}